// Round 3
// baseline (1351.455 us; speedup 1.0000x reference)
//
#include <hip/hip_runtime.h>
#include <hip/hip_bf16.h>

typedef __hip_bfloat16 bf16;

__device__ __forceinline__ float dssp(float x){
  // softplus(x) - log(2), numerically stable
  return fmaxf(x, 0.f) + log1pf(expf(-fabsf(x))) - 0.693147180559945f;
}
__device__ __forceinline__ int clampi(int x, int lo, int hi){ return x<lo?lo:(x>hi?hi:x); }

constexpr int TBL_K    = 4096;
constexpr int TBL_ROWS = TBL_K + 1;   // rows 0..4096 inclusive, d = r*5/4096
constexpr int TBL_TILES = (TBL_ROWS + 31) / 32;  // 129

// ------------------------------------------------- dtype detection ----------
// bf16 storage: low 16 bits of each word are a bf16 with exponent in a narrow
// band for N(0,0.05) data. f32 storage: low 16 bits are uniform mantissa bits.
__global__ void detect_mode(const unsigned* __restrict__ raw, int* flag){
  __shared__ int c;
  int t = threadIdx.x;
  if (t==0) c = 0;
  __syncthreads();
  unsigned u  = raw[t];            // first 1 KiB of emb_table buffer (safe: >=25 KiB)
  unsigned lo = u & 0xFFFFu;
  int e = (int)((lo >> 7) & 0xFF);
  int ok = (lo==0u) || (e >= 0x70 && e <= 0x8F);
  atomicAdd(&c, ok);
  __syncthreads();
  if (t==0) *flag = (c >= 160) ? 1 : 0;   // 1 = bf16 storage, 0 = f32 storage
}

// ---------------------------------------------- canonical fp32 conversion ---
struct Seg { const void* src; float* dst; int n; };
struct SegTable { Seg s[27]; int count; long total; };

__global__ void convert_all(SegTable tbl, const int* __restrict__ flag){
  int mode = *flag;
  long tid    = (long)blockIdx.x*blockDim.x + threadIdx.x;
  long stride = (long)gridDim.x*blockDim.x;
  for (long i=tid; i<tbl.total; i+=stride){
    long off = i; int k = 0;
    while (k < tbl.count-1 && off >= tbl.s[k].n){ off -= tbl.s[k].n; k++; }
    float f;
    if (mode) f = __bfloat162float(((const bf16*)tbl.s[k].src)[off]);
    else      f = ((const float*)tbl.s[k].src)[off];
    tbl.s[k].dst[off] = (f==f) ? f : 0.f;    // NaN scrub at the single choke point
  }
}

// ------------------------------------------------------------------ setup ---
__global__ void init_all(int* cnt_r, int* cnt_h, float* uacc,
                         int2* spk_r, int2* spk_h, int N, int E, int EH){
  int t = blockIdx.x*blockDim.x + threadIdx.x;
  if (t < N){ cnt_r[t]=0; cnt_h[t]=0; }
  if (t < 64) uacc[t]=0.f;
  if (t < E)  spk_r[t]=make_int2(0,0);   // holes (if any) read node 0, d=0: finite
  if (t < EH) spk_h[t]=make_int2(0,0);
}

__global__ void count_edges(const int* __restrict__ ei, const int* __restrict__ eih,
                            int E, int EH, int N, int* cnt_r, int* cnt_h){
  int t = blockIdx.x*blockDim.x + threadIdx.x;
  if (t < E)  atomicAdd(&cnt_r[clampi(ei[E + t], 0, N-1)], 1);
  if (t < EH) atomicAdd(&cnt_h[clampi(eih[EH + t], 0, N-1)], 1);
}

__global__ __launch_bounds__(256) void scan_pair(const int* cnt_r, int* off_r, int* cur_r,
                                                 const int* cnt_h, int* off_h, int* cur_h, int N){
  __shared__ int s[256];
  int t = threadIdx.x;
  int CH = (N + 255) / 256;
  for (int which=0; which<2; which++){
    const int* cnt = which? cnt_h : cnt_r;
    int* off = which? off_h : off_r;
    int* cur = which? cur_h : cur_r;
    int base = t*CH;
    int sum = 0;
    for (int q=0;q<CH;q++){ int idx=base+q; sum += (idx<N)? cnt[idx] : 0; }
    __syncthreads();
    s[t]=sum; __syncthreads();
    for (int ofs=1; ofs<256; ofs<<=1){
      int v = s[t]; int vp = (t>=ofs)? s[t-ofs] : 0;
      __syncthreads(); s[t]=v+vp; __syncthreads();
    }
    int run = (t>0)? s[t-1] : 0;
    for (int q=0;q<CH;q++){
      int idx=base+q;
      if (idx<N){ off[idx]=run; cur[idx]=run; run += cnt[idx]; }
    }
    if (t==255) off[N] = s[255];
  }
}

__global__ void scatter_edges(const int* __restrict__ ei, const float* __restrict__ distc,
                              const int* __restrict__ eih, int E, int EH, int N,
                              int* cur_r, int* cur_h, int2* spk_r, int2* spk_h){
  int t = blockIdx.x*blockDim.x + threadIdx.x;
  if (t < E){
    int i = clampi(ei[E+t], 0, N-1);
    int p = clampi(atomicAdd(&cur_r[i], 1), 0, E-1);
    spk_r[p] = make_int2(clampi(ei[t],0,N-1), __float_as_int(distc[t])); // (src j, dist f32 bits)
  }
  if (t < EH){
    int ih = clampi(eih[EH+t], 0, N-1);
    int p = clampi(atomicAdd(&cur_h[ih], 1), 0, EH-1);
    spk_h[p] = make_int2(clampi(eih[t],0,N-1), t);                       // (src jh, hull-edge id)
  }
}

__global__ void embed_v(const int* __restrict__ z, const float* __restrict__ emb,
                        float* __restrict__ v, int N){
  int t = blockIdx.x*blockDim.x + threadIdx.x;
  if (t < N*128){ int n=t>>7, f=t&127; v[t] = emb[clampi(z[n],0,99)*128 + f]; }
}

// --------------------------------------------------- W(dist) lookup tables ---
__global__ __launch_bounds__(256) void build_wtab(const float* __restrict__ mlp_w1,
    const float* __restrict__ mlp_b1, const float* __restrict__ mlp_w2,
    const float* __restrict__ mlp_b2, float* __restrict__ Wtab){
  int l    = blockIdx.x / TBL_TILES;
  int tile = blockIdx.x % TBL_TILES;
  int row0 = tile * 32;
  const float* w1 = mlp_w1 + l*128*25;
  const float* b1 = mlp_b1 + l*128;
  const float* w2 = mlp_w2 + l*128*128;
  const float* b2 = mlp_b2 + l*128;
  __shared__ float Gs[32][26];
  __shared__ float Ts[32][129];
  __shared__ float Ws[32][129];
  int t = threadIdx.x;
  for (int idx=t; idx<32*25; idx+=256){
    int r = idx/25, k = idx%25;
    float d = (row0+r) * (5.0f/4096.0f);
    float x = d - (float)k*(5.0f/24.0f);
    Gs[r][k] = expf(-11.52f*x*x);     // coeff = -0.5/(5/24)^2 = -11.52
  }
  __syncthreads();
  int rg = t&7, cg = t>>3;
  #pragma unroll
  for (int ri=0;ri<4;ri++){
    int r = rg*4+ri;
    #pragma unroll
    for (int ci=0;ci<4;ci++){
      int c = cg*4+ci;
      float s = b1[c];
      for (int k=0;k<25;k++) s += Gs[r][k]*w1[c*25+k];
      Ts[r][c] = dssp(s);
    }
  }
  float acc[4][4] = {};
  for (int k0=0;k0<128;k0+=32){
    __syncthreads();
    for (int idx=t; idx<32*128; idx+=256){
      int c = idx>>5, kk = idx&31;
      Ws[kk][c] = w2[c*128 + k0 + kk];
    }
    __syncthreads();
    for (int kk=0;kk<32;kk++){
      float xv[4];
      #pragma unroll
      for (int ri=0;ri<4;ri++) xv[ri]=Ts[rg*4+ri][k0+kk];
      #pragma unroll
      for (int ci=0;ci<4;ci++){
        float wv = Ws[kk][cg*4+ci];
        #pragma unroll
        for (int ri=0;ri<4;ri++) acc[ri][ci] += xv[ri]*wv;
      }
    }
  }
  #pragma unroll
  for (int ri=0;ri<4;ri++){
    int r = row0 + rg*4 + ri;
    if (r >= TBL_ROWS) continue;
    float d  = r * (5.0f/4096.0f);
    float Cf = 0.5f*(cosf(d*(3.14159265358979f/5.0f))+1.0f);
    #pragma unroll
    for (int ci=0;ci<4;ci++){
      int c = cg*4+ci;
      Wtab[((size_t)l*TBL_ROWS + r)*128 + c] = (acc[ri][ci] + b2[c]) * Cf;
    }
  }
}

// ------------------------------------------------------------ generic GEMM ---
// Y[r][c] = act( bias[c] + sum_k X[r][k] * W[c][k] ), K=128 fixed, C in {64,128}
// In-place (Y==X) safe: block reads only its own 32-row tile (staged to LDS,
// __syncthreads before stores) and writes only those rows.
template<int C, bool SSP>
__global__ __launch_bounds__(256) void gemm_k128(const float* __restrict__ X,
    const float* __restrict__ W, const float* __restrict__ Bias,
    float* __restrict__ Y, int nrows){
  constexpr int CPT = C/32;           // cols per thread (4 or 2)
  __shared__ float Xs[32][129];
  __shared__ float Ws[32][C+1];
  int t = threadIdx.x;
  int row0 = blockIdx.x*32;
  for (int idx=t; idx<32*128; idx+=256){
    int r = idx>>7, k = idx&127;
    int gr = row0+r;
    Xs[r][k] = (gr<nrows)? X[(size_t)gr*128+k] : 0.f;
  }
  int rg = t&7, cg = t>>3;
  float acc[4][CPT];
  #pragma unroll
  for (int ri=0;ri<4;ri++)
    #pragma unroll
    for (int ci=0;ci<CPT;ci++) acc[ri][ci]=0.f;
  for (int k0=0;k0<128;k0+=32){
    __syncthreads();
    for (int idx=t; idx<32*C; idx+=256){
      int c = idx>>5, kk = idx&31;
      Ws[kk][c] = W[c*128 + k0 + kk];
    }
    __syncthreads();
    for (int kk=0;kk<32;kk++){
      float xv[4];
      #pragma unroll
      for (int ri=0;ri<4;ri++) xv[ri] = Xs[rg*4+ri][k0+kk];
      #pragma unroll
      for (int ci=0;ci<CPT;ci++){
        float wv = Ws[kk][cg*CPT+ci];
        #pragma unroll
        for (int ri=0;ri<4;ri++) acc[ri][ci] += xv[ri]*wv;
      }
    }
  }
  __syncthreads();                    // all LDS reads done before (in-place) stores
  #pragma unroll
  for (int ri=0;ri<4;ri++){
    int gr = row0 + rg*4 + ri;
    if (gr>=nrows) continue;
    #pragma unroll
    for (int ci=0;ci<CPT;ci++){
      int c = cg*CPT+ci;
      float y = acc[ri][ci] + (Bias? Bias[c] : 0.f);
      if (SSP) y = dssp(y);
      Y[(size_t)gr*C + c] = y;
    }
  }
}

// ------------------------------------------- hull filter, in sorted order ---
__global__ __launch_bounds__(256) void hull_W(const int2* __restrict__ spk_h,
    const float* __restrict__ fea, const float* __restrict__ w1, const float* __restrict__ b1,
    const float* __restrict__ w2, const float* __restrict__ b2,
    float* __restrict__ WhS, int EH){
  int row0 = blockIdx.x*32;
  __shared__ float Fs[32][8];
  __shared__ float Ts[32][129];
  __shared__ float Ws[32][129];
  int t = threadIdx.x;
  for (int idx=t; idx<32*7; idx+=256){
    int r = idx/7, k = idx%7;
    int p = row0 + r;
    int eid = (p<EH) ? clampi(spk_h[p].y, 0, EH-1) : 0;
    Fs[r][k] = (p<EH) ? fea[(size_t)eid*7 + k] : 0.f;
  }
  __syncthreads();
  int rg=t&7, cg=t>>3;
  #pragma unroll
  for (int ri=0;ri<4;ri++){
    int r = rg*4+ri;
    #pragma unroll
    for (int ci=0;ci<4;ci++){
      int c = cg*4+ci;
      float s = b1[c];
      #pragma unroll
      for (int k=0;k<7;k++) s += Fs[r][k]*w1[c*7+k];
      Ts[r][c] = dssp(s);
    }
  }
  float acc[4][4]={};
  for (int k0=0;k0<128;k0+=32){
    __syncthreads();
    for (int idx=t; idx<32*128; idx+=256){
      int c = idx>>5, kk = idx&31;
      Ws[kk][c] = w2[c*128+k0+kk];
    }
    __syncthreads();
    for (int kk=0;kk<32;kk++){
      float xv[4];
      #pragma unroll
      for (int ri=0;ri<4;ri++) xv[ri]=Ts[rg*4+ri][k0+kk];
      #pragma unroll
      for (int ci=0;ci<4;ci++){
        float wv = Ws[kk][cg*4+ci];
        #pragma unroll
        for (int ri=0;ri<4;ri++) acc[ri][ci] += xv[ri]*wv;
      }
    }
  }
  #pragma unroll
  for (int ri=0;ri<4;ri++){
    int p = row0+rg*4+ri;
    if (p>=EH) continue;
    #pragma unroll
    for (int ci=0;ci<4;ci++){
      int c=cg*4+ci;
      WhS[(size_t)p*128+c] = acc[ri][ci] + b2[c];
    }
  }
}

// --------------------------------------------------- CSR segment reductions ---
__global__ __launch_bounds__(128) void acc_radius(const int* __restrict__ off,
    const int2* __restrict__ spk, const float* __restrict__ vlin,
    const float* __restrict__ Wt, float* __restrict__ accO, int Etot, int N){
  int n = blockIdx.x, f = threadIdx.x;
  int b = clampi(off[n],   0, Etot);
  int e = clampi(off[n+1], b, Etot);
  float a = 0.f;
  for (int p=b;p<e;p++){
    int2 pk = spk[p];
    float d = __int_as_float(pk.y);                          // f32 dist
    float x = fminf(fmaxf(d * (4096.0f/5.0f), 0.f), 4096.0f); // NaN-suppressing
    int i0 = (int)x;
    if (i0 > TBL_K-1) i0 = TBL_K-1;
    float fr = x - (float)i0;
    const float* rp = Wt + (size_t)i0*128 + f;
    float w0 = rp[0], w1v = rp[128];
    int j = clampi(pk.x, 0, N-1);
    a += vlin[(size_t)j*128 + f] * (w0 + fr*(w1v-w0));
  }
  accO[(size_t)n*128+f] = a;
}

__global__ __launch_bounds__(128) void acc_hull(const int* __restrict__ off,
    const int2* __restrict__ spk, const float* __restrict__ vlinh,
    const float* __restrict__ WhS, float* __restrict__ accO, int EHtot, int N){
  int n = blockIdx.x, f = threadIdx.x;
  int b = clampi(off[n],   0, EHtot);
  int e = clampi(off[n+1], b, EHtot);
  float a = 0.f;
  for (int p=b;p<e;p++){
    int2 pk = spk[p];
    int j = clampi(pk.x, 0, N-1);
    a += vlinh[(size_t)j*128+f] * WhS[(size_t)p*128+f];
  }
  accO[(size_t)n*128+f] = a;
}

// --------------------------------------- concat-matmul + residual update ---
__global__ __launch_bounds__(256) void cat_update(const float* __restrict__ o64,
    const float* __restrict__ oh64, const float* __restrict__ cw, const float* __restrict__ cb,
    float* __restrict__ v, int N){
  __shared__ float Xs[32][65];
  __shared__ float Ws[32][129];
  int t=threadIdx.x; int row0=blockIdx.x*32;
  int rg=t&7, cg=t>>3;
  float acc[4][4]={};
  for (int half=0; half<2; half++){
    const float* X = half? oh64 : o64;
    __syncthreads();
    for (int idx=t; idx<32*64; idx+=256){
      int r=idx>>6, k=idx&63;
      int gr=row0+r;
      Xs[r][k] = (gr<N)? X[(size_t)gr*64+k] : 0.f;
    }
    for (int k0=0;k0<64;k0+=32){
      __syncthreads();
      for (int idx=t; idx<32*128; idx+=256){
        int f=idx>>5, kk=idx&31;
        Ws[kk][f] = cw[f*128 + half*64 + k0 + kk];
      }
      __syncthreads();
      for (int kk=0;kk<32;kk++){
        float xv[4];
        #pragma unroll
        for (int ri=0;ri<4;ri++) xv[ri]=Xs[rg*4+ri][k0+kk];
        #pragma unroll
        for (int ci=0;ci<4;ci++){
          float wv=Ws[kk][cg*4+ci];
          #pragma unroll
          for (int ri=0;ri<4;ri++) acc[ri][ci]+=xv[ri]*wv;
        }
      }
    }
  }
  #pragma unroll
  for (int ri=0;ri<4;ri++){
    int gr=row0+rg*4+ri; if (gr>=N) continue;
    #pragma unroll
    for (int ci=0;ci<4;ci++){
      int c=cg*4+ci;
      v[(size_t)gr*128+c] += dssp(acc[ri][ci] + cb[c]);
    }
  }
}

// ------------------------------------------------------- readout (update_u) ---
__global__ __launch_bounds__(256) void final_u(const float* __restrict__ v,
    const float* __restrict__ u1w, const float* __restrict__ u1b,
    const float* __restrict__ u2w, const float* __restrict__ u2b,
    const int* __restrict__ batch, float* __restrict__ uacc, int N){
  __shared__ float Xs[32][129];
  __shared__ float Ws[32][65];
  __shared__ float Ts[32][65];
  int t=threadIdx.x; int row0=blockIdx.x*32;
  for (int idx=t; idx<32*128; idx+=256){
    int r=idx>>7,k=idx&127; int gr=row0+r;
    Xs[r][k]=(gr<N)? v[(size_t)gr*128+k]:0.f;
  }
  int rg=t&7, cg=t>>3;
  float acc[4][2]={};
  for (int k0=0;k0<128;k0+=32){
    __syncthreads();
    for (int idx=t; idx<32*64; idx+=256){
      int c=idx>>5, kk=idx&31;
      Ws[kk][c]=u1w[c*128+k0+kk];
    }
    __syncthreads();
    for (int kk=0;kk<32;kk++){
      float xv[4];
      #pragma unroll
      for (int ri=0;ri<4;ri++) xv[ri]=Xs[rg*4+ri][k0+kk];
      #pragma unroll
      for (int ci=0;ci<2;ci++){
        float wv=Ws[kk][cg*2+ci];
        #pragma unroll
        for (int ri=0;ri<4;ri++) acc[ri][ci]+=xv[ri]*wv;
      }
    }
  }
  #pragma unroll
  for (int ri=0;ri<4;ri++)
    #pragma unroll
    for (int ci=0;ci<2;ci++)
      Ts[rg*4+ri][cg*2+ci] = dssp(acc[ri][ci]+u1b[cg*2+ci]);
  __syncthreads();
  if (t<32){
    int gr=row0+t;
    if (gr<N){
      float s=u2b[0];
      for (int c=0;c<64;c++) s += Ts[t][c]*u2w[c];
      atomicAdd(&uacc[clampi(batch[gr],0,63)], s);
    }
  }
}

__global__ void write_out(const float* __restrict__ uacc, void* out, const int* __restrict__ flag){
  int t = threadIdx.x;
  if (t < 64){
    if (*flag) ((bf16*)out)[t] = __float2bfloat16(uacc[t]);
    else       ((float*)out)[t] = uacc[t];
  }
}

// ----------------------------------------------------------------- launch ---
extern "C" void kernel_launch(void* const* d_in, const int* in_sizes, int n_in,
                              void* d_out, int out_size, void* d_ws, size_t ws_size,
                              hipStream_t stream){
  const int* z     = (const int*)d_in[0];
  const int* ei    = (const int*)d_in[1];
  const int* eih   = (const int*)d_in[2];
  const int* batch = (const int*)d_in[3];

  const int N  = in_sizes[0];
  const int E  = in_sizes[1]/2;
  const int EH = in_sizes[2]/2;

  char* wp = (char*)d_ws;
  auto alloc = [&](size_t bytes)->char*{
    char* p = wp; wp += (bytes + 255) & ~(size_t)255; return p;
  };
  int* flag    = (int*)alloc(256);
  int* cnt_r   = (int*)alloc((size_t)N*4);
  int* off_r   = (int*)alloc((size_t)(N+1)*4);
  int* cur_r   = (int*)alloc((size_t)N*4);
  int* cnt_h   = (int*)alloc((size_t)N*4);
  int* off_h   = (int*)alloc((size_t)(N+1)*4);
  int* cur_h   = (int*)alloc((size_t)N*4);
  int2* spk_r  = (int2*)alloc((size_t)E*8);
  int2* spk_h  = (int2*)alloc((size_t)EH*8);
  float* uacc  = (float*)alloc(64*4);

  // canonical fp32 copies of all float inputs (d_in[4..30])
  SegTable tbl; tbl.count = 27; tbl.total = 0;
  float* cvt[27];
  for (int i=0;i<27;i++){
    int n = in_sizes[4+i];
    cvt[i] = (float*)alloc((size_t)n*4);
    tbl.s[i].src = d_in[4+i];
    tbl.s[i].dst = cvt[i];
    tbl.s[i].n   = n;
    tbl.total   += n;
  }
  const float* distc   = cvt[0];
  const float* feac    = cvt[1];
  const float* embc    = cvt[2];
  const float* lin_w   = cvt[3];
  const float* mlp_w1  = cvt[4];
  const float* mlp_b1  = cvt[5];
  const float* mlp_w2  = cvt[6];
  const float* mlp_b2  = cvt[7];
  const float* linh_w  = cvt[8];
  const float* mlph_w1 = cvt[9];
  const float* mlph_b1 = cvt[10];
  const float* mlph_w2 = cvt[11];
  const float* mlph_b2 = cvt[12];
  const float* v1_w  = cvt[13];
  const float* v1_b  = cvt[14];
  const float* v2_w  = cvt[15];
  const float* v2_b  = cvt[16];
  const float* vh1_w = cvt[17];
  const float* vh1_b = cvt[18];
  const float* vh2_w = cvt[19];
  const float* vh2_b = cvt[20];
  const float* cat_w = cvt[21];
  const float* cat_b = cvt[22];
  const float* u1_w  = cvt[23];
  const float* u1_b  = cvt[24];
  const float* u2_w  = cvt[25];
  const float* u2_b  = cvt[26];

  float* Wtab  = (float*)alloc((size_t)4*TBL_ROWS*128*sizeof(float));
  float* v     = (float*)alloc((size_t)N*128*4);
  float* vlin  = (float*)alloc((size_t)N*128*4);
  float* vlinh = (float*)alloc((size_t)N*128*4);
  float* accR  = (float*)alloc((size_t)N*128*4);   // reused in-place as z1
  float* accH  = (float*)alloc((size_t)N*128*4);   // reused in-place as z1h
  float* o64   = (float*)alloc((size_t)N*64*4);
  float* oh64  = (float*)alloc((size_t)N*64*4);
  float* WhS   = (float*)alloc((size_t)EH*128*4);

  detect_mode<<<1,256,0,stream>>>((const unsigned*)d_in[6], flag);
  {
    int cb = (int)((tbl.total + 255)/256);
    if (cb > 8192) cb = 8192;
    convert_all<<<cb,256,0,stream>>>(tbl, flag);
  }

  int nb;
  nb = (E+255)/256;     init_all<<<nb,256,0,stream>>>(cnt_r,cnt_h,uacc,spk_r,spk_h,N,E,EH);
  nb = (E+255)/256;     count_edges<<<nb,256,0,stream>>>(ei,eih,E,EH,N,cnt_r,cnt_h);
  scan_pair<<<1,256,0,stream>>>(cnt_r,off_r,cur_r,cnt_h,off_h,cur_h,N);
  nb = (E+255)/256;     scatter_edges<<<nb,256,0,stream>>>(ei,distc,eih,E,EH,N,cur_r,cur_h,spk_r,spk_h);
  nb = (N*128+255)/256; embed_v<<<nb,256,0,stream>>>(z,embc,v,N);
  build_wtab<<<4*TBL_TILES,256,0,stream>>>(mlp_w1,mlp_b1,mlp_w2,mlp_b2,Wtab);

  const int nt = (N+31)/32;
  const int ht = (EH+31)/32;
  for (int l=0;l<4;l++){
    gemm_k128<128,false><<<nt,256,0,stream>>>(v, lin_w  + l*16384, nullptr, vlin,  N);
    gemm_k128<128,false><<<nt,256,0,stream>>>(v, linh_w + l*16384, nullptr, vlinh, N);
    hull_W<<<ht,256,0,stream>>>(spk_h, feac, mlph_w1 + l*896, mlph_b1 + l*128,
                                mlph_w2 + l*16384, mlph_b2 + l*128, WhS, EH);
    acc_radius<<<N,128,0,stream>>>(off_r, spk_r, vlin, Wtab + (size_t)l*TBL_ROWS*128, accR, E, N);
    acc_hull  <<<N,128,0,stream>>>(off_h, spk_h, vlinh, WhS, accH, EH, N);
    gemm_k128<128,true ><<<nt,256,0,stream>>>(accR, v1_w  + l*16384, v1_b  + l*128, accR, N); // in-place
    gemm_k128<64 ,false><<<nt,256,0,stream>>>(accR, v2_w  + l*8192,  v2_b  + l*64,  o64,  N);
    gemm_k128<128,true ><<<nt,256,0,stream>>>(accH, vh1_w + l*16384, vh1_b + l*128, accH, N); // in-place
    gemm_k128<64 ,false><<<nt,256,0,stream>>>(accH, vh2_w + l*8192,  vh2_b + l*64,  oh64, N);
    cat_update<<<nt,256,0,stream>>>(o64, oh64, cat_w + l*16384, cat_b + l*128, v, N);
  }
  final_u<<<nt,256,0,stream>>>(v, u1_w, u1_b, u2_w, u2_b, batch, uacc, N);
  write_out<<<1,64,0,stream>>>(uacc, d_out, flag);
}

// Round 4
// 977.813 us; speedup vs baseline: 1.3821x; 1.3821x over previous
//
#include <hip/hip_runtime.h>
#include <hip/hip_bf16.h>

typedef __hip_bfloat16 bf16;

__device__ __forceinline__ float dssp(float x){
  return fmaxf(x, 0.f) + log1pf(expf(-fabsf(x))) - 0.693147180559945f;
}
__device__ __forceinline__ int clampi(int x, int lo, int hi){ return x<lo?lo:(x>hi?hi:x); }
// bf16 <-> f32 via bit ops (round-to-nearest-even encode; finite inputs)
__device__ __forceinline__ unsigned short f2b(float f){
  unsigned x = __float_as_uint(f);
  return (unsigned short)((x + 0x7fffu + ((x>>16)&1u)) >> 16);
}
__device__ __forceinline__ float b2f16(unsigned short u){ return __uint_as_float(((unsigned)u)<<16); }

constexpr int TBL_K    = 4096;
constexpr int TBL_ROWS = TBL_K + 1;
constexpr int TBL_TILES = (TBL_ROWS + 31) / 32;  // 129

// ------------------------------------------------- dtype detection ----------
__global__ void detect_mode(const unsigned* __restrict__ raw, int* flag){
  __shared__ int c;
  int t = threadIdx.x;
  if (t==0) c = 0;
  __syncthreads();
  unsigned u  = raw[t];
  unsigned lo = u & 0xFFFFu;
  int e = (int)((lo >> 7) & 0xFF);
  int ok = (lo==0u) || (e >= 0x70 && e <= 0x8F);
  atomicAdd(&c, ok);
  __syncthreads();
  if (t==0) *flag = (c >= 160) ? 1 : 0;   // 1 = bf16 storage, 0 = f32 storage
}

// ---------------------------------------------- canonical fp32 conversion ---
struct Seg { const void* src; float* dst; int n; };
struct SegTable { Seg s[27]; int count; long total; };

__global__ void convert_all(SegTable tbl, const int* __restrict__ flag){
  int mode = *flag;
  long tid    = (long)blockIdx.x*blockDim.x + threadIdx.x;
  long stride = (long)gridDim.x*blockDim.x;
  for (long i=tid; i<tbl.total; i+=stride){
    long off = i; int k = 0;
    while (k < tbl.count-1 && off >= tbl.s[k].n){ off -= tbl.s[k].n; k++; }
    float f;
    if (mode) f = __bfloat162float(((const bf16*)tbl.s[k].src)[off]);
    else      f = ((const float*)tbl.s[k].src)[off];
    tbl.s[k].dst[off] = (f==f) ? f : 0.f;    // NaN scrub at the single choke point
  }
}

// ------------------------------------------------------------------ setup ---
__global__ void init_all(int* cnt_r, int* cnt_h, float* uacc,
                         int2* spk_r, int2* spk_h, int N, int E, int EH){
  int t = blockIdx.x*blockDim.x + threadIdx.x;
  if (t < N){ cnt_r[t]=0; cnt_h[t]=0; }
  if (t < 64) uacc[t]=0.f;
  if (t < E)  spk_r[t]=make_int2(0,0);
  if (t < EH) spk_h[t]=make_int2(0,0);
}

__global__ void count_edges(const int* __restrict__ ei, const int* __restrict__ eih,
                            int E, int EH, int N, int* cnt_r, int* cnt_h){
  int t = blockIdx.x*blockDim.x + threadIdx.x;
  if (t < E)  atomicAdd(&cnt_r[clampi(ei[E + t], 0, N-1)], 1);
  if (t < EH) atomicAdd(&cnt_h[clampi(eih[EH + t], 0, N-1)], 1);
}

__global__ __launch_bounds__(256) void scan_pair(const int* cnt_r, int* off_r, int* cur_r,
                                                 const int* cnt_h, int* off_h, int* cur_h, int N){
  __shared__ int s[256];
  int t = threadIdx.x;
  int CH = (N + 255) / 256;
  for (int which=0; which<2; which++){
    const int* cnt = which? cnt_h : cnt_r;
    int* off = which? off_h : off_r;
    int* cur = which? cur_h : cur_r;
    int base = t*CH;
    int sum = 0;
    for (int q=0;q<CH;q++){ int idx=base+q; sum += (idx<N)? cnt[idx] : 0; }
    __syncthreads();
    s[t]=sum; __syncthreads();
    for (int ofs=1; ofs<256; ofs<<=1){
      int v = s[t]; int vp = (t>=ofs)? s[t-ofs] : 0;
      __syncthreads(); s[t]=v+vp; __syncthreads();
    }
    int run = (t>0)? s[t-1] : 0;
    for (int q=0;q<CH;q++){
      int idx=base+q;
      if (idx<N){ off[idx]=run; cur[idx]=run; run += cnt[idx]; }
    }
    if (t==255) off[N] = s[255];
  }
}

__global__ void scatter_edges(const int* __restrict__ ei, const float* __restrict__ distc,
                              const int* __restrict__ eih, int E, int EH, int N,
                              int* cur_r, int* cur_h, int2* spk_r, int2* spk_h){
  int t = blockIdx.x*blockDim.x + threadIdx.x;
  if (t < E){
    int i = clampi(ei[E+t], 0, N-1);
    int p = clampi(atomicAdd(&cur_r[i], 1), 0, E-1);
    spk_r[p] = make_int2(clampi(ei[t],0,N-1), __float_as_int(distc[t]));
  }
  if (t < EH){
    int ih = clampi(eih[EH+t], 0, N-1);
    int p = clampi(atomicAdd(&cur_h[ih], 1), 0, EH-1);
    spk_h[p] = make_int2(clampi(eih[t],0,N-1), t);
  }
}

__global__ void embed_v(const int* __restrict__ z, const float* __restrict__ emb,
                        float* __restrict__ v, int N){
  int t = blockIdx.x*blockDim.x + threadIdx.x;
  if (t < N*32){
    int n=t>>5, q=t&31;
    float4 f = ((const float4*)(emb + (size_t)clampi(z[n],0,99)*128))[q];
    ((float4*)(v + (size_t)n*128))[q] = f;
  }
}

// --------------------------------------------------- W(dist) lookup tables ---
__global__ __launch_bounds__(256) void build_wtab(const float* __restrict__ mlp_w1,
    const float* __restrict__ mlp_b1, const float* __restrict__ mlp_w2,
    const float* __restrict__ mlp_b2, float* __restrict__ Wtab){
  int l    = blockIdx.x / TBL_TILES;
  int tile = blockIdx.x % TBL_TILES;
  int row0 = tile * 32;
  const float* w1 = mlp_w1 + l*128*25;
  const float* b1 = mlp_b1 + l*128;
  const float* w2 = mlp_w2 + l*128*128;
  const float* b2 = mlp_b2 + l*128;
  __shared__ float Gs[32][26];
  __shared__ float Ts[32][129];
  __shared__ float Ws[32][129];
  int t = threadIdx.x;
  for (int idx=t; idx<32*25; idx+=256){
    int r = idx/25, k = idx%25;
    float d = (row0+r) * (5.0f/4096.0f);
    float x = d - (float)k*(5.0f/24.0f);
    Gs[r][k] = expf(-11.52f*x*x);
  }
  __syncthreads();
  int rg = t&7, cg = t>>3;
  #pragma unroll
  for (int ri=0;ri<4;ri++){
    int r = rg*4+ri;
    #pragma unroll
    for (int ci=0;ci<4;ci++){
      int c = cg*4+ci;
      float s = b1[c];
      for (int k=0;k<25;k++) s += Gs[r][k]*w1[c*25+k];
      Ts[r][c] = dssp(s);
    }
  }
  float acc[4][4] = {};
  for (int k0=0;k0<128;k0+=32){
    __syncthreads();
    for (int idx=t; idx<1024; idx+=256){
      int c=idx>>3, kk4=(idx&7)*4;
      float4 f = ((const float4*)(w2+(size_t)c*128+k0))[idx&7];
      Ws[kk4][c]=f.x; Ws[kk4+1][c]=f.y; Ws[kk4+2][c]=f.z; Ws[kk4+3][c]=f.w;
    }
    __syncthreads();
    for (int kk=0;kk<32;kk++){
      float xv[4];
      #pragma unroll
      for (int ri=0;ri<4;ri++) xv[ri]=Ts[rg*4+ri][k0+kk];
      #pragma unroll
      for (int ci=0;ci<4;ci++){
        float wv = Ws[kk][cg*4+ci];
        #pragma unroll
        for (int ri=0;ri<4;ri++) acc[ri][ci] += xv[ri]*wv;
      }
    }
  }
  #pragma unroll
  for (int ri=0;ri<4;ri++){
    int r = row0 + rg*4 + ri;
    if (r >= TBL_ROWS) continue;
    float d  = r * (5.0f/4096.0f);
    float Cf = 0.5f*(cosf(d*(3.14159265358979f/5.0f))+1.0f);
    #pragma unroll
    for (int ci=0;ci<4;ci++){
      int c = cg*4+ci;
      Wtab[((size_t)l*TBL_ROWS + r)*128 + c] = (acc[ri][ci] + b2[c]) * Cf;
    }
  }
}

// pack rows r,r+1 into one uint (lo=w(r), hi=w(r+1)) per [l][r][f], r<4096
__global__ void pack_wtab(const float* __restrict__ Wtab, unsigned* __restrict__ Wpk){
  long t = (long)blockIdx.x*blockDim.x + threadIdx.x;
  const long TOT = 4L*TBL_K*128;
  if (t < TOT){
    int l = (int)(t / ((long)TBL_K*128));
    long rem = t % ((long)TBL_K*128);
    int r = (int)(rem >> 7), f = (int)(rem & 127);
    const float* base = Wtab + (size_t)l*TBL_ROWS*128;
    unsigned lo = f2b(base[(size_t)r*128+f]);
    unsigned hi = f2b(base[(size_t)(r+1)*128+f]);
    Wpk[t] = (hi<<16)|lo;
  }
}

// ---------------------------------------- fused lin+linh (bf16 outputs) -----
__global__ __launch_bounds__(256) void lin2(const float* __restrict__ v,
    const float* __restrict__ wA, const float* __restrict__ wB,
    unsigned short* __restrict__ outA, unsigned short* __restrict__ outB, int N){
  __shared__ float Xs[32][129];
  __shared__ float Ws[32][129];
  int t=threadIdx.x; int row0=blockIdx.x*32;
  int rg=t&7, cg=t>>3;
  for (int idx=t; idx<1024; idx+=256){
    int r=idx>>5, k4=(idx&31)*4; int gr=row0+r;
    float4 f = (gr<N)? ((const float4*)(v+(size_t)gr*128))[idx&31] : make_float4(0,0,0,0);
    Xs[r][k4]=f.x; Xs[r][k4+1]=f.y; Xs[r][k4+2]=f.z; Xs[r][k4+3]=f.w;
  }
  float aA[4][4]={}, aB[4][4]={};
  for (int k0=0;k0<128;k0+=32){
    __syncthreads();
    for (int idx=t; idx<1024; idx+=256){
      int c=idx>>3, kk4=(idx&7)*4;
      float4 f = ((const float4*)(wA+(size_t)c*128+k0))[idx&7];
      Ws[kk4][c]=f.x; Ws[kk4+1][c]=f.y; Ws[kk4+2][c]=f.z; Ws[kk4+3][c]=f.w;
    }
    __syncthreads();
    for (int kk=0;kk<32;kk++){
      float xv[4];
      #pragma unroll
      for (int ri=0;ri<4;ri++) xv[ri]=Xs[rg*4+ri][k0+kk];
      #pragma unroll
      for (int ci=0;ci<4;ci++){
        float wv=Ws[kk][cg*4+ci];
        #pragma unroll
        for (int ri=0;ri<4;ri++) aA[ri][ci]+=xv[ri]*wv;
      }
    }
  }
  for (int k0=0;k0<128;k0+=32){
    __syncthreads();
    for (int idx=t; idx<1024; idx+=256){
      int c=idx>>3, kk4=(idx&7)*4;
      float4 f = ((const float4*)(wB+(size_t)c*128+k0))[idx&7];
      Ws[kk4][c]=f.x; Ws[kk4+1][c]=f.y; Ws[kk4+2][c]=f.z; Ws[kk4+3][c]=f.w;
    }
    __syncthreads();
    for (int kk=0;kk<32;kk++){
      float xv[4];
      #pragma unroll
      for (int ri=0;ri<4;ri++) xv[ri]=Xs[rg*4+ri][k0+kk];
      #pragma unroll
      for (int ci=0;ci<4;ci++){
        float wv=Ws[kk][cg*4+ci];
        #pragma unroll
        for (int ri=0;ri<4;ri++) aB[ri][ci]+=xv[ri]*wv;
      }
    }
  }
  #pragma unroll
  for (int ri=0;ri<4;ri++){
    int gr=row0+rg*4+ri; if (gr>=N) continue;
    #pragma unroll
    for (int ci=0;ci<4;ci++){
      int c=cg*4+ci;
      outA[(size_t)gr*128+c]=f2b(aA[ri][ci]);
      outB[(size_t)gr*128+c]=f2b(aB[ri][ci]);
    }
  }
}

// ------------------------------------------- hull filter (bf16 output) ------
__global__ __launch_bounds__(256) void hull_W(const int2* __restrict__ spk_h,
    const float* __restrict__ fea, const float* __restrict__ w1, const float* __restrict__ b1,
    const float* __restrict__ w2, const float* __restrict__ b2,
    unsigned short* __restrict__ WhS, int EH){
  int row0 = blockIdx.x*32;
  __shared__ float Fs[32][8];
  __shared__ float Ts[32][129];
  __shared__ float Ws[32][129];
  int t = threadIdx.x;
  for (int idx=t; idx<32*7; idx+=256){
    int r = idx/7, k = idx%7;
    int p = row0 + r;
    int eid = (p<EH) ? clampi(spk_h[p].y, 0, EH-1) : 0;
    Fs[r][k] = (p<EH) ? fea[(size_t)eid*7 + k] : 0.f;
  }
  __syncthreads();
  int rg=t&7, cg=t>>3;
  #pragma unroll
  for (int ri=0;ri<4;ri++){
    int r = rg*4+ri;
    #pragma unroll
    for (int ci=0;ci<4;ci++){
      int c = cg*4+ci;
      float s = b1[c];
      #pragma unroll
      for (int k=0;k<7;k++) s += Fs[r][k]*w1[c*7+k];
      Ts[r][c] = dssp(s);
    }
  }
  float acc[4][4]={};
  for (int k0=0;k0<128;k0+=32){
    __syncthreads();
    for (int idx=t; idx<1024; idx+=256){
      int c=idx>>3, kk4=(idx&7)*4;
      float4 f = ((const float4*)(w2+(size_t)c*128+k0))[idx&7];
      Ws[kk4][c]=f.x; Ws[kk4+1][c]=f.y; Ws[kk4+2][c]=f.z; Ws[kk4+3][c]=f.w;
    }
    __syncthreads();
    for (int kk=0;kk<32;kk++){
      float xv[4];
      #pragma unroll
      for (int ri=0;ri<4;ri++) xv[ri]=Ts[rg*4+ri][k0+kk];
      #pragma unroll
      for (int ci=0;ci<4;ci++){
        float wv = Ws[kk][cg*4+ci];
        #pragma unroll
        for (int ri=0;ri<4;ri++) acc[ri][ci] += xv[ri]*wv;
      }
    }
  }
  #pragma unroll
  for (int ri=0;ri<4;ri++){
    int p = row0+rg*4+ri;
    if (p>=EH) continue;
    #pragma unroll
    for (int ci=0;ci<4;ci++){
      int c=cg*4+ci;
      WhS[(size_t)p*128+c] = f2b(acc[ri][ci] + b2[c]);
    }
  }
}

// ------------------------------ CSR segment reductions (radius + hull) ------
__global__ __launch_bounds__(128) void acc_both(
    const int* __restrict__ off_r, const int2* __restrict__ spk_r,
    const unsigned short* __restrict__ vlin, const unsigned* __restrict__ Wpk,
    float* __restrict__ accR,
    const int* __restrict__ off_h, const int2* __restrict__ spk_h,
    const unsigned short* __restrict__ vlinh, const unsigned short* __restrict__ WhS,
    float* __restrict__ accH,
    int Etot, int EHtot, int N){
  int f = threadIdx.x;
  if ((int)blockIdx.x < N){
    int n = blockIdx.x;
    int b = clampi(off_r[n], 0, Etot);
    int e = clampi(off_r[n+1], b, Etot);
    float a = 0.f;
    int p = b;
    for (; p+2<=e; p+=2){
      int2 kA = spk_r[p], kB = spk_r[p+1];
      float dA = __int_as_float(kA.y), dB = __int_as_float(kB.y);
      float xA = fminf(fmaxf(dA*(4096.0f/5.0f),0.f),4096.f);
      float xB = fminf(fmaxf(dB*(4096.0f/5.0f),0.f),4096.f);
      int iA=(int)xA; if(iA>TBL_K-1)iA=TBL_K-1;
      int iB=(int)xB; if(iB>TBL_K-1)iB=TBL_K-1;
      float frA=xA-(float)iA, frB=xB-(float)iB;
      unsigned uA = Wpk[(size_t)iA*128+f];
      unsigned uB = Wpk[(size_t)iB*128+f];
      float vA = b2f16(vlin[(size_t)clampi(kA.x,0,N-1)*128+f]);
      float vB = b2f16(vlin[(size_t)clampi(kB.x,0,N-1)*128+f]);
      float w0A=b2f16((unsigned short)(uA&0xFFFFu)), w1A=b2f16((unsigned short)(uA>>16));
      float w0B=b2f16((unsigned short)(uB&0xFFFFu)), w1B=b2f16((unsigned short)(uB>>16));
      a += vA*(w0A+frA*(w1A-w0A)) + vB*(w0B+frB*(w1B-w0B));
    }
    if (p<e){
      int2 kA = spk_r[p];
      float dA = __int_as_float(kA.y);
      float xA = fminf(fmaxf(dA*(4096.0f/5.0f),0.f),4096.f);
      int iA=(int)xA; if(iA>TBL_K-1)iA=TBL_K-1;
      float frA=xA-(float)iA;
      unsigned uA = Wpk[(size_t)iA*128+f];
      float vA = b2f16(vlin[(size_t)clampi(kA.x,0,N-1)*128+f]);
      float w0A=b2f16((unsigned short)(uA&0xFFFFu)), w1A=b2f16((unsigned short)(uA>>16));
      a += vA*(w0A+frA*(w1A-w0A));
    }
    accR[(size_t)n*128+f] = a;
  } else {
    int n = blockIdx.x - N;
    int b = clampi(off_h[n], 0, EHtot);
    int e = clampi(off_h[n+1], b, EHtot);
    float a = 0.f;
    int p = b;
    for (; p+2<=e; p+=2){
      int2 kA = spk_h[p], kB = spk_h[p+1];
      float vA = b2f16(vlinh[(size_t)clampi(kA.x,0,N-1)*128+f]);
      float vB = b2f16(vlinh[(size_t)clampi(kB.x,0,N-1)*128+f]);
      a += vA*b2f16(WhS[(size_t)p*128+f]) + vB*b2f16(WhS[(size_t)(p+1)*128+f]);
    }
    if (p<e){
      int2 kA = spk_h[p];
      float vA = b2f16(vlinh[(size_t)clampi(kA.x,0,N-1)*128+f]);
      a += vA*b2f16(WhS[(size_t)p*128+f]);
    }
    accH[(size_t)n*128+f] = a;
  }
}

// ---------------- fused update_v: (v1,v2)+(vh1,vh2)+cat+residual ------------
__global__ __launch_bounds__(256) void update_v_fused(
    const float* __restrict__ accR, const float* __restrict__ accH,
    const float* __restrict__ v1w, const float* __restrict__ v1b,
    const float* __restrict__ v2w, const float* __restrict__ v2b,
    const float* __restrict__ vh1w, const float* __restrict__ vh1b,
    const float* __restrict__ vh2w, const float* __restrict__ vh2b,
    const float* __restrict__ cw, const float* __restrict__ cb,
    float* __restrict__ v, int N){
  __shared__ float Xs[32][129];   // doubles as T buffer
  __shared__ float Ws[32][129];
  __shared__ float Os[32][129];   // [o64 | oh64]
  int t=threadIdx.x; int row0=blockIdx.x*32;
  int rg=t&7, cg=t>>3;

  for (int path=0; path<2; path++){
    const float* X  = path? accH : accR;
    const float* W1 = path? vh1w : v1w;
    const float* B1 = path? vh1b : v1b;
    const float* W2 = path? vh2w : v2w;
    const float* B2 = path? vh2b : v2b;
    __syncthreads();   // prior-path Xs reads complete
    for (int idx=t; idx<1024; idx+=256){
      int r=idx>>5, k4=(idx&31)*4; int gr=row0+r;
      float4 f = (gr<N)? ((const float4*)(X+(size_t)gr*128))[idx&31] : make_float4(0,0,0,0);
      Xs[r][k4]=f.x; Xs[r][k4+1]=f.y; Xs[r][k4+2]=f.z; Xs[r][k4+3]=f.w;
    }
    // T = ssp(X@W1^T + b1)
    float a1[4][4]={};
    for (int k0=0;k0<128;k0+=32){
      __syncthreads();
      for (int idx=t; idx<1024; idx+=256){
        int c=idx>>3, kk4=(idx&7)*4;
        float4 f = ((const float4*)(W1+(size_t)c*128+k0))[idx&7];
        Ws[kk4][c]=f.x; Ws[kk4+1][c]=f.y; Ws[kk4+2][c]=f.z; Ws[kk4+3][c]=f.w;
      }
      __syncthreads();
      for (int kk=0;kk<32;kk++){
        float xv[4];
        #pragma unroll
        for (int ri=0;ri<4;ri++) xv[ri]=Xs[rg*4+ri][k0+kk];
        #pragma unroll
        for (int ci=0;ci<4;ci++){
          float wv=Ws[kk][cg*4+ci];
          #pragma unroll
          for (int ri=0;ri<4;ri++) a1[ri][ci]+=xv[ri]*wv;
        }
      }
    }
    __syncthreads();   // all Xs reads done before overwriting with T
    #pragma unroll
    for (int ri=0;ri<4;ri++)
      #pragma unroll
      for (int ci=0;ci<4;ci++)
        Xs[rg*4+ri][cg*4+ci] = dssp(a1[ri][ci] + B1[cg*4+ci]);
    // o = T@W2^T + b2  (64 cols)
    float a2[4][2]={};
    for (int k0=0;k0<128;k0+=32){
      __syncthreads();
      for (int idx=t; idx<512; idx+=256){
        int c=idx>>3, kk4=(idx&7)*4;
        float4 f = ((const float4*)(W2+(size_t)c*128+k0))[idx&7];
        Ws[kk4][c]=f.x; Ws[kk4+1][c]=f.y; Ws[kk4+2][c]=f.z; Ws[kk4+3][c]=f.w;
      }
      __syncthreads();
      for (int kk=0;kk<32;kk++){
        float xv[4];
        #pragma unroll
        for (int ri=0;ri<4;ri++) xv[ri]=Xs[rg*4+ri][k0+kk];
        #pragma unroll
        for (int ci=0;ci<2;ci++){
          float wv=Ws[kk][cg*2+ci];
          #pragma unroll
          for (int ri=0;ri<4;ri++) a2[ri][ci]+=xv[ri]*wv;
        }
      }
    }
    #pragma unroll
    for (int ri=0;ri<4;ri++)
      #pragma unroll
      for (int ci=0;ci<2;ci++)
        Os[rg*4+ri][path*64+cg*2+ci] = a2[ri][ci] + B2[cg*2+ci];
  }
  // v += ssp(Os@cw^T + cb)
  float a3[4][4]={};
  for (int k0=0;k0<128;k0+=32){
    __syncthreads();
    for (int idx=t; idx<1024; idx+=256){
      int c=idx>>3, kk4=(idx&7)*4;
      float4 f = ((const float4*)(cw+(size_t)c*128+k0))[idx&7];
      Ws[kk4][c]=f.x; Ws[kk4+1][c]=f.y; Ws[kk4+2][c]=f.z; Ws[kk4+3][c]=f.w;
    }
    __syncthreads();
    for (int kk=0;kk<32;kk++){
      float xv[4];
      #pragma unroll
      for (int ri=0;ri<4;ri++) xv[ri]=Os[rg*4+ri][k0+kk];
      #pragma unroll
      for (int ci=0;ci<4;ci++){
        float wv=Ws[kk][cg*4+ci];
        #pragma unroll
        for (int ri=0;ri<4;ri++) a3[ri][ci]+=xv[ri]*wv;
      }
    }
  }
  #pragma unroll
  for (int ri=0;ri<4;ri++){
    int gr=row0+rg*4+ri; if (gr>=N) continue;
    #pragma unroll
    for (int ci=0;ci<4;ci++){
      int c=cg*4+ci;
      v[(size_t)gr*128+c] += dssp(a3[ri][ci] + cb[c]);
    }
  }
}

// ------------------------------------------------------- readout (update_u) ---
__global__ __launch_bounds__(256) void final_u(const float* __restrict__ v,
    const float* __restrict__ u1w, const float* __restrict__ u1b,
    const float* __restrict__ u2w, const float* __restrict__ u2b,
    const int* __restrict__ batch, float* __restrict__ uacc, int N){
  __shared__ float Xs[32][129];
  __shared__ float Ws[32][65];
  __shared__ float Ts[32][65];
  __shared__ float ss[32];
  __shared__ int   bb[32];
  int t=threadIdx.x; int row0=blockIdx.x*32;
  for (int idx=t; idx<1024; idx+=256){
    int r=idx>>5, k4=(idx&31)*4; int gr=row0+r;
    float4 f = (gr<N)? ((const float4*)(v+(size_t)gr*128))[idx&31] : make_float4(0,0,0,0);
    Xs[r][k4]=f.x; Xs[r][k4+1]=f.y; Xs[r][k4+2]=f.z; Xs[r][k4+3]=f.w;
  }
  int rg=t&7, cg=t>>3;
  float acc[4][2]={};
  for (int k0=0;k0<128;k0+=32){
    __syncthreads();
    for (int idx=t; idx<512; idx+=256){
      int c=idx>>3, kk4=(idx&7)*4;
      float4 f = ((const float4*)(u1w+(size_t)c*128+k0))[idx&7];
      Ws[kk4][c]=f.x; Ws[kk4+1][c]=f.y; Ws[kk4+2][c]=f.z; Ws[kk4+3][c]=f.w;
    }
    __syncthreads();
    for (int kk=0;kk<32;kk++){
      float xv[4];
      #pragma unroll
      for (int ri=0;ri<4;ri++) xv[ri]=Xs[rg*4+ri][k0+kk];
      #pragma unroll
      for (int ci=0;ci<2;ci++){
        float wv=Ws[kk][cg*2+ci];
        #pragma unroll
        for (int ri=0;ri<4;ri++) acc[ri][ci]+=xv[ri]*wv;
      }
    }
  }
  #pragma unroll
  for (int ri=0;ri<4;ri++)
    #pragma unroll
    for (int ci=0;ci<2;ci++)
      Ts[rg*4+ri][cg*2+ci] = dssp(acc[ri][ci]+u1b[cg*2+ci]);
  __syncthreads();
  if (t<32){
    int gr=row0+t;
    float s=0.f; int bt=-1;
    if (gr<N){
      s=u2b[0];
      for (int c=0;c<64;c++) s += Ts[t][c]*u2w[c];
      bt = clampi(batch[gr],0,63);
    }
    ss[t]=s; bb[t]=bt;
  }
  __syncthreads();
  if (t==0){
    // batch is sorted -> few runs per 32-row tile; one atomic per run
    float run=0.f; int cur=-1;
    for (int q=0;q<32;q++){
      int bq=bb[q];
      if (bq<0) continue;
      if (bq!=cur){ if (cur>=0) atomicAdd(&uacc[cur],run); cur=bq; run=0.f; }
      run += ss[q];
    }
    if (cur>=0) atomicAdd(&uacc[cur],run);
  }
}

__global__ void write_out(const float* __restrict__ uacc, void* out, const int* __restrict__ flag){
  int t = threadIdx.x;
  if (t < 64){
    if (*flag) ((bf16*)out)[t] = __float2bfloat16(uacc[t]);
    else       ((float*)out)[t] = uacc[t];
  }
}

// ----------------------------------------------------------------- launch ---
extern "C" void kernel_launch(void* const* d_in, const int* in_sizes, int n_in,
                              void* d_out, int out_size, void* d_ws, size_t ws_size,
                              hipStream_t stream){
  const int* z     = (const int*)d_in[0];
  const int* ei    = (const int*)d_in[1];
  const int* eih   = (const int*)d_in[2];
  const int* batch = (const int*)d_in[3];

  const int N  = in_sizes[0];
  const int E  = in_sizes[1]/2;
  const int EH = in_sizes[2]/2;

  char* wp = (char*)d_ws;
  auto alloc = [&](size_t bytes)->char*{
    char* p = wp; wp += (bytes + 255) & ~(size_t)255; return p;
  };
  int* flag    = (int*)alloc(256);
  int* cnt_r   = (int*)alloc((size_t)N*4);
  int* off_r   = (int*)alloc((size_t)(N+1)*4);
  int* cur_r   = (int*)alloc((size_t)N*4);
  int* cnt_h   = (int*)alloc((size_t)N*4);
  int* off_h   = (int*)alloc((size_t)(N+1)*4);
  int* cur_h   = (int*)alloc((size_t)N*4);
  int2* spk_r  = (int2*)alloc((size_t)E*8);
  int2* spk_h  = (int2*)alloc((size_t)EH*8);
  float* uacc  = (float*)alloc(64*4);

  // canonical fp32 copies of all float inputs (d_in[4..30])
  SegTable tbl; tbl.count = 27; tbl.total = 0;
  float* cvt[27];
  for (int i=0;i<27;i++){
    int n = in_sizes[4+i];
    cvt[i] = (float*)alloc((size_t)n*4);
    tbl.s[i].src = d_in[4+i];
    tbl.s[i].dst = cvt[i];
    tbl.s[i].n   = n;
    tbl.total   += n;
  }
  const float* distc   = cvt[0];
  const float* feac    = cvt[1];
  const float* embc    = cvt[2];
  const float* lin_w   = cvt[3];
  const float* mlp_w1  = cvt[4];
  const float* mlp_b1  = cvt[5];
  const float* mlp_w2  = cvt[6];
  const float* mlp_b2  = cvt[7];
  const float* linh_w  = cvt[8];
  const float* mlph_w1 = cvt[9];
  const float* mlph_b1 = cvt[10];
  const float* mlph_w2 = cvt[11];
  const float* mlph_b2 = cvt[12];
  const float* v1_w  = cvt[13];
  const float* v1_b  = cvt[14];
  const float* v2_w  = cvt[15];
  const float* v2_b  = cvt[16];
  const float* vh1_w = cvt[17];
  const float* vh1_b = cvt[18];
  const float* vh2_w = cvt[19];
  const float* vh2_b = cvt[20];
  const float* cat_w = cvt[21];
  const float* cat_b = cvt[22];
  const float* u1_w  = cvt[23];
  const float* u1_b  = cvt[24];
  const float* u2_w  = cvt[25];
  const float* u2_b  = cvt[26];

  float*    Wtab  = (float*)alloc((size_t)4*TBL_ROWS*128*4);
  unsigned* Wpk   = (unsigned*)alloc((size_t)4*TBL_K*128*4);
  float* v     = (float*)alloc((size_t)N*128*4);
  unsigned short* vlin  = (unsigned short*)alloc((size_t)N*128*2);
  unsigned short* vlinh = (unsigned short*)alloc((size_t)N*128*2);
  float* accR  = (float*)alloc((size_t)N*128*4);
  float* accH  = (float*)alloc((size_t)N*128*4);
  unsigned short* WhS = (unsigned short*)alloc((size_t)EH*128*2);

  detect_mode<<<1,256,0,stream>>>((const unsigned*)d_in[6], flag);
  {
    int cb = (int)((tbl.total + 255)/256);
    if (cb > 4096) cb = 4096;
    convert_all<<<cb,256,0,stream>>>(tbl, flag);
  }

  int nb;
  nb = (E+255)/256;     init_all<<<nb,256,0,stream>>>(cnt_r,cnt_h,uacc,spk_r,spk_h,N,E,EH);
  nb = (E+255)/256;     count_edges<<<nb,256,0,stream>>>(ei,eih,E,EH,N,cnt_r,cnt_h);
  scan_pair<<<1,256,0,stream>>>(cnt_r,off_r,cur_r,cnt_h,off_h,cur_h,N);
  nb = (E+255)/256;     scatter_edges<<<nb,256,0,stream>>>(ei,distc,eih,E,EH,N,cur_r,cur_h,spk_r,spk_h);
  nb = (N*32+255)/256;  embed_v<<<nb,256,0,stream>>>(z,embc,v,N);
  build_wtab<<<4*TBL_TILES,256,0,stream>>>(mlp_w1,mlp_b1,mlp_w2,mlp_b2,Wtab);
  pack_wtab<<<(int)((4L*TBL_K*128+255)/256),256,0,stream>>>(Wtab,Wpk);

  const int nt = (N+31)/32;
  const int ht = (EH+31)/32;
  for (int l=0;l<4;l++){
    lin2<<<nt,256,0,stream>>>(v, lin_w + l*16384, linh_w + l*16384, vlin, vlinh, N);
    hull_W<<<ht,256,0,stream>>>(spk_h, feac, mlph_w1 + l*896, mlph_b1 + l*128,
                                mlph_w2 + l*16384, mlph_b2 + l*128, WhS, EH);
    acc_both<<<2*N,128,0,stream>>>(off_r, spk_r, vlin, Wpk + (size_t)l*TBL_K*128, accR,
                                   off_h, spk_h, vlinh, WhS, accH, E, EH, N);
    update_v_fused<<<nt,256,0,stream>>>(accR, accH,
        v1_w + l*16384, v1_b + l*128, v2_w + l*8192, v2_b + l*64,
        vh1_w + l*16384, vh1_b + l*128, vh2_w + l*8192, vh2_b + l*64,
        cat_w + l*16384, cat_b + l*128, v, N);
  }
  final_u<<<nt,256,0,stream>>>(v, u1_w, u1_b, u2_w, u2_b, batch, uacc, N);
  write_out<<<1,64,0,stream>>>(uacc, d_out, flag);
}